// Round 1
// baseline (502.772 us; speedup 1.0000x reference)
//
#include <hip/hip_runtime.h>

// ResidualNetwork forward, fp32, MI355X (gfx950).
// N=4194304 points, DIN=3, H=10, L=10 residual blocks, DOUT=1.
// Strategy: 1 thread = 1 point. Hidden state in VGPRs. Weights accessed at
// wave-uniform, compile-time-constant offsets from const __restrict__ pointers
// -> compiler emits s_load into SGPRs, FMAs are v_fmac_f32 v,s,v.
// Compute-bound: ~6.5 kFLOP/point fp32 on the vector ALU (no fp32 MFMA).

#define NPTS 4194304
#define H 10
#define L 10

__global__ __launch_bounds__(256) void resnet_fwd(
    const float* __restrict__ x,
    const float* __restrict__ w0, const float* __restrict__ b0,
    const float* __restrict__ w1, const float* __restrict__ b1,
    const float* __restrict__ Wr1, const float* __restrict__ Br1,
    const float* __restrict__ Wr2, const float* __restrict__ Br2,
    const float* __restrict__ Wr3, const float* __restrict__ Br3,
    const float* __restrict__ w8, const float* __restrict__ b8,
    const float* __restrict__ w9, const float* __restrict__ b9,
    float* __restrict__ out)
{
    const int i = blockIdx.x * blockDim.x + threadIdx.x;
    if (i >= NPTS) return;

    // x is [N,3] row-major: 12B per thread, compiler merges to dwordx3.
    const float x0 = x[3 * i + 0];
    const float x1 = x[3 * i + 1];
    const float x2 = x[3 * i + 2];

    float h[H];   // current hidden state
    float t1[H];  // h1 within a block
    float t2[H];  // h2 accumulator within a block

    // ---- layer 0: 3 -> 10, relu ----
#pragma unroll
    for (int j = 0; j < H; ++j) {
        float a = b0[j];
        a = fmaf(x0, w0[0 * H + j], a);
        a = fmaf(x1, w0[1 * H + j], a);
        a = fmaf(x2, w0[2 * H + j], a);
        h[j] = fmaxf(a, 0.0f);
    }

    // ---- layer 1: 10 -> 10, relu ----
#pragma unroll
    for (int j = 0; j < H; ++j) t1[j] = b1[j];
#pragma unroll
    for (int k = 0; k < H; ++k) {
#pragma unroll
        for (int j = 0; j < H; ++j) {
            t1[j] = fmaf(h[k], w1[k * H + j], t1[j]);
        }
    }
#pragma unroll
    for (int j = 0; j < H; ++j) h[j] = fmaxf(t1[j], 0.0f);

    // ---- L residual blocks ----
    // keep as a real loop (unroll 1) so only one block's weights (~330 floats)
    // are live in SGPRs at a time.
#pragma unroll 1
    for (int l = 0; l < L; ++l) {
        const float* __restrict__ W1 = Wr1 + l * H * H;
        const float* __restrict__ B1 = Br1 + l * H;
        const float* __restrict__ W2 = Wr2 + l * H * H;
        const float* __restrict__ B2 = Br2 + l * H;
        const float* __restrict__ W3 = Wr3 + l * H * H;
        const float* __restrict__ B3 = Br3 + l * H;

        // h1 = relu(h @ W1 + B1)
#pragma unroll
        for (int j = 0; j < H; ++j) t1[j] = B1[j];
#pragma unroll
        for (int k = 0; k < H; ++k) {
#pragma unroll
            for (int j = 0; j < H; ++j) {
                t1[j] = fmaf(h[k], W1[k * H + j], t1[j]);
            }
        }
#pragma unroll
        for (int j = 0; j < H; ++j) t1[j] = fmaxf(t1[j], 0.0f);

        // h2 = relu(h1 @ W3 + B3 + h @ W2 + B2)
#pragma unroll
        for (int j = 0; j < H; ++j) t2[j] = B3[j] + B2[j];
#pragma unroll
        for (int k = 0; k < H; ++k) {
#pragma unroll
            for (int j = 0; j < H; ++j) {
                t2[j] = fmaf(h[k], W2[k * H + j], t2[j]);
            }
        }
#pragma unroll
        for (int k = 0; k < H; ++k) {
#pragma unroll
            for (int j = 0; j < H; ++j) {
                t2[j] = fmaf(t1[k], W3[k * H + j], t2[j]);
            }
        }
#pragma unroll
        for (int j = 0; j < H; ++j) h[j] = fmaxf(t2[j], 0.0f);
    }

    // ---- layer 8: 10 -> 10, relu ----
#pragma unroll
    for (int j = 0; j < H; ++j) t1[j] = b8[j];
#pragma unroll
    for (int k = 0; k < H; ++k) {
#pragma unroll
        for (int j = 0; j < H; ++j) {
            t1[j] = fmaf(h[k], w8[k * H + j], t1[j]);
        }
    }
#pragma unroll
    for (int j = 0; j < H; ++j) h[j] = fmaxf(t1[j], 0.0f);

    // ---- output layer: 10 -> 1, no activation ----
    float o = b9[0];
#pragma unroll
    for (int k = 0; k < H; ++k) o = fmaf(h[k], w9[k], o);

    out[i] = o;
}

extern "C" void kernel_launch(void* const* d_in, const int* in_sizes, int n_in,
                              void* d_out, int out_size, void* d_ws, size_t ws_size,
                              hipStream_t stream)
{
    const float* x   = (const float*)d_in[0];
    const float* w0  = (const float*)d_in[1];
    const float* b0  = (const float*)d_in[2];
    const float* w1  = (const float*)d_in[3];
    const float* b1  = (const float*)d_in[4];
    const float* Wr1 = (const float*)d_in[5];
    const float* Br1 = (const float*)d_in[6];
    const float* Wr2 = (const float*)d_in[7];
    const float* Br2 = (const float*)d_in[8];
    const float* Wr3 = (const float*)d_in[9];
    const float* Br3 = (const float*)d_in[10];
    const float* w8  = (const float*)d_in[11];
    const float* b8  = (const float*)d_in[12];
    const float* w9  = (const float*)d_in[13];
    const float* b9  = (const float*)d_in[14];
    float* out = (float*)d_out;

    dim3 block(256);
    dim3 grid(NPTS / 256);
    hipLaunchKernelGGL(resnet_fwd, grid, block, 0, stream,
                       x, w0, b0, w1, b1, Wr1, Br1, Wr2, Br2, Wr3, Br3,
                       w8, b8, w9, b9, out);
}

// Round 2
// 352.861 us; speedup vs baseline: 1.4248x; 1.4248x over previous
//
#include <hip/hip_runtime.h>

// ResidualNetwork forward, fp32, MI355X (gfx950).
// Round 2: pack 2 points per thread into float2 so every weight-FMA becomes
// one v_pk_fma_f32 (VOP3P, 2 fp32 FMA/instr on CDNA) and every relu one
// v_pk_max_f32. Weights stay wave-uniform (SGPR via s_load), broadcast into
// both halves. Cuts non-FMA VALU per useful FMA ~2x and, if pk-fp32 is
// full-rate, halves FMA instruction count too.
// __launch_bounds__(256,4): 128-VGPR budget, peak live state ~75 VGPRs.

#define NPTS 4194304
#define H 10
#define L 10

typedef float v2f __attribute__((ext_vector_type(2)));

__device__ __forceinline__ v2f bc(float s) { v2f r; r.x = s; r.y = s; return r; }
__device__ __forceinline__ v2f fma2(v2f a, float w, v2f c) {
    return __builtin_elementwise_fma(a, bc(w), c);
}
__device__ __forceinline__ v2f relu2(v2f a) {
    return __builtin_elementwise_max(a, bc(0.0f));
}

__global__ __launch_bounds__(256, 4) void resnet_fwd(
    const float* __restrict__ x,
    const float* __restrict__ w0, const float* __restrict__ b0,
    const float* __restrict__ w1, const float* __restrict__ b1,
    const float* __restrict__ Wr1, const float* __restrict__ Br1,
    const float* __restrict__ Wr2, const float* __restrict__ Br2,
    const float* __restrict__ Wr3, const float* __restrict__ Br3,
    const float* __restrict__ w8, const float* __restrict__ b8,
    const float* __restrict__ w9, const float* __restrict__ b9,
    float* __restrict__ out)
{
    const int i = blockIdx.x * blockDim.x + threadIdx.x;  // pair index, 2 points
    // points 2i and 2i+1; x is [N,3] row-major -> 24 consecutive bytes/thread
    const float* xp = x + 6 * (long)i;
    const float xa0 = xp[0], xa1 = xp[1], xa2 = xp[2];
    const float xb0 = xp[3], xb1 = xp[4], xb2 = xp[5];
    v2f X0; X0.x = xa0; X0.y = xb0;
    v2f X1; X1.x = xa1; X1.y = xb1;
    v2f X2; X2.x = xa2; X2.y = xb2;

    v2f h[H];   // current hidden state (pair-packed)
    v2f t1[H];  // h1 within a block
    v2f t2[H];  // h2 accumulator within a block

    // ---- layer 0: 3 -> 10, relu ----
#pragma unroll
    for (int j = 0; j < H; ++j) {
        v2f a = bc(b0[j]);
        a = fma2(X0, w0[0 * H + j], a);
        a = fma2(X1, w0[1 * H + j], a);
        a = fma2(X2, w0[2 * H + j], a);
        h[j] = relu2(a);
    }

    // ---- layer 1: 10 -> 10, relu ----
#pragma unroll
    for (int j = 0; j < H; ++j) t1[j] = bc(b1[j]);
#pragma unroll
    for (int k = 0; k < H; ++k) {
#pragma unroll
        for (int j = 0; j < H; ++j) {
            t1[j] = fma2(h[k], w1[k * H + j], t1[j]);
        }
    }
#pragma unroll
    for (int j = 0; j < H; ++j) h[j] = relu2(t1[j]);

    // ---- L residual blocks (keep as real loop: bounds live weights/SGPRs) ----
#pragma unroll 1
    for (int l = 0; l < L; ++l) {
        const float* __restrict__ W1 = Wr1 + l * H * H;
        const float* __restrict__ B1 = Br1 + l * H;
        const float* __restrict__ W2 = Wr2 + l * H * H;
        const float* __restrict__ B2 = Br2 + l * H;
        const float* __restrict__ W3 = Wr3 + l * H * H;
        const float* __restrict__ B3 = Br3 + l * H;

        // t1 = relu(h @ W1 + B1)
#pragma unroll
        for (int j = 0; j < H; ++j) t1[j] = bc(B1[j]);
#pragma unroll
        for (int k = 0; k < H; ++k) {
#pragma unroll
            for (int j = 0; j < H; ++j) {
                t1[j] = fma2(h[k], W1[k * H + j], t1[j]);
            }
        }
#pragma unroll
        for (int j = 0; j < H; ++j) t1[j] = relu2(t1[j]);

        // t2 = B3 + B2 + h @ W2   (h dies after this)
#pragma unroll
        for (int j = 0; j < H; ++j) t2[j] = bc(B3[j] + B2[j]);
#pragma unroll
        for (int k = 0; k < H; ++k) {
#pragma unroll
            for (int j = 0; j < H; ++j) {
                t2[j] = fma2(h[k], W2[k * H + j], t2[j]);
            }
        }

        // t2 += t1 @ W3 ; h = relu(t2)
#pragma unroll
        for (int k = 0; k < H; ++k) {
#pragma unroll
            for (int j = 0; j < H; ++j) {
                t2[j] = fma2(t1[k], W3[k * H + j], t2[j]);
            }
        }
#pragma unroll
        for (int j = 0; j < H; ++j) h[j] = relu2(t2[j]);
    }

    // ---- layer 8: 10 -> 10, relu ----
#pragma unroll
    for (int j = 0; j < H; ++j) t1[j] = bc(b8[j]);
#pragma unroll
    for (int k = 0; k < H; ++k) {
#pragma unroll
        for (int j = 0; j < H; ++j) {
            t1[j] = fma2(h[k], w8[k * H + j], t1[j]);
        }
    }
#pragma unroll
    for (int j = 0; j < H; ++j) h[j] = relu2(t1[j]);

    // ---- output layer: 10 -> 1 ----
    v2f o = bc(b9[0]);
#pragma unroll
    for (int k = 0; k < H; ++k) o = fma2(h[k], w9[k], o);

    // two consecutive outputs -> one dwordx2 store
    *(v2f*)(out + 2 * (long)i) = o;
}

extern "C" void kernel_launch(void* const* d_in, const int* in_sizes, int n_in,
                              void* d_out, int out_size, void* d_ws, size_t ws_size,
                              hipStream_t stream)
{
    const float* x   = (const float*)d_in[0];
    const float* w0  = (const float*)d_in[1];
    const float* b0  = (const float*)d_in[2];
    const float* w1  = (const float*)d_in[3];
    const float* b1  = (const float*)d_in[4];
    const float* Wr1 = (const float*)d_in[5];
    const float* Br1 = (const float*)d_in[6];
    const float* Wr2 = (const float*)d_in[7];
    const float* Br2 = (const float*)d_in[8];
    const float* Wr3 = (const float*)d_in[9];
    const float* Br3 = (const float*)d_in[10];
    const float* w8  = (const float*)d_in[11];
    const float* b8  = (const float*)d_in[12];
    const float* w9  = (const float*)d_in[13];
    const float* b9  = (const float*)d_in[14];
    float* out = (float*)d_out;

    dim3 block(256);
    dim3 grid(NPTS / 2 / 256);   // 2 points per thread
    hipLaunchKernelGGL(resnet_fwd, grid, block, 0, stream,
                       x, w0, b0, w1, b1, Wr1, Br1, Wr2, Br2, Wr3, Br3,
                       w8, b8, w9, b9, out);
}

// Round 3
// 351.541 us; speedup vs baseline: 1.4302x; 1.0038x over previous
//
#include <hip/hip_runtime.h>

// ResidualNetwork forward, fp32, MI355X (gfx950).
// Round 3: weights prepacked (by a tiny kernel, every call) into d_ws as
// DUPLICATED float2 pairs (w,w) in exact use order. Uniform float2 load ->
// s_load_dwordx2 -> aligned SGPR pair -> direct 64-bit SGPR operand of
// v_pk_fma_f32 (no per-weight VGPR materialization, which was ~1400 extra
// VALU instrs/thread in round 2). B2+B3 pre-folded (same numerics as r2).
// Stream layout (float2 entries):
//   [0,40)      layer0 interleaved: per j: b0[j], w0[0][j], w0[1][j], w0[2][j]
//   [40,150)    layer1: b1[10], w1[100] (k-major)
//   [150,3350)  10 blocks x 320: B1[10], W1[100], (B2+B3)[10], W2[100], W3[100]
//   [3350,3460) layer8: b8[10], w8[100]
//   [3460,3471) out: b9[1], w9[10]

#define NPTS 4194304
#define H 10
#define L 10

#define L1_OFF 40
#define BLK_OFF 150
#define BLK_STRIDE 320
#define L8_OFF 3350
#define L9_OFF 3460
#define NENT 3471

typedef float v2f __attribute__((ext_vector_type(2)));

__device__ __forceinline__ v2f tov2(float2 w) { v2f r; r.x = w.x; r.y = w.y; return r; }
__device__ __forceinline__ v2f bc(float s) { v2f r; r.x = s; r.y = s; return r; }
__device__ __forceinline__ v2f fma2p(v2f a, float2 w, v2f c) {
    return __builtin_elementwise_fma(a, tov2(w), c);
}
__device__ __forceinline__ v2f relu2(v2f a) {
    return __builtin_elementwise_max(a, bc(0.0f));
}

// ---------------- prepack: scatter weights into use-order duplicated pairs ----
__global__ __launch_bounds__(256) void prepack(
    const float* __restrict__ w0, const float* __restrict__ b0,
    const float* __restrict__ w1, const float* __restrict__ b1,
    const float* __restrict__ Wr1, const float* __restrict__ Br1,
    const float* __restrict__ Wr2, const float* __restrict__ Br2,
    const float* __restrict__ Wr3, const float* __restrict__ Br3,
    const float* __restrict__ w8, const float* __restrict__ b8,
    const float* __restrict__ w9, const float* __restrict__ b9,
    float2* __restrict__ wp)
{
    for (int idx = threadIdx.x; idx < NENT; idx += 256) {
        float v;
        if (idx < L1_OFF) {                       // layer0 interleaved
            int j = idx >> 2, r = idx & 3;
            v = (r == 0) ? b0[j] : w0[(r - 1) * H + j];
        } else if (idx < BLK_OFF) {               // layer1
            int e = idx - L1_OFF;
            v = (e < H) ? b1[e] : w1[e - H];
        } else if (idx < L8_OFF) {                // residual blocks
            int e = idx - BLK_OFF;
            int l = e / BLK_STRIDE, m = e % BLK_STRIDE;
            if      (m < 10)  v = Br1[l * H + m];
            else if (m < 110) v = Wr1[l * H * H + (m - 10)];
            else if (m < 120) v = Br2[l * H + (m - 110)] + Br3[l * H + (m - 110)];
            else if (m < 220) v = Wr2[l * H * H + (m - 120)];
            else              v = Wr3[l * H * H + (m - 220)];
        } else if (idx < L9_OFF) {                // layer8
            int e = idx - L8_OFF;
            v = (e < H) ? b8[e] : w8[e - H];
        } else {                                  // output layer
            int e = idx - L9_OFF;
            v = (e == 0) ? b9[0] : w9[e - 1];
        }
        float2 d; d.x = v; d.y = v;
        wp[idx] = d;
    }
}

// ---------------- main kernel: 2 points/thread, pk-fp32 ----------------------
__global__ __launch_bounds__(256, 4) void resnet_fwd(
    const float* __restrict__ x,
    const float2* __restrict__ wp,
    float* __restrict__ out)
{
    const int i = blockIdx.x * blockDim.x + threadIdx.x;  // pair index
    const float* xp = x + 6 * (long)i;
    v2f X0; X0.x = xp[0]; X0.y = xp[3];
    v2f X1; X1.x = xp[1]; X1.y = xp[4];
    v2f X2; X2.x = xp[2]; X2.y = xp[5];

    v2f h[H], t1[H], t2[H];

    // ---- layer 0: 3 -> 10, relu ----
#pragma unroll
    for (int j = 0; j < H; ++j) {
        v2f a = tov2(wp[4 * j]);
        a = fma2p(X0, wp[4 * j + 1], a);
        a = fma2p(X1, wp[4 * j + 2], a);
        a = fma2p(X2, wp[4 * j + 3], a);
        h[j] = relu2(a);
    }

    // ---- layer 1: 10 -> 10, relu ----
#pragma unroll
    for (int j = 0; j < H; ++j) t1[j] = tov2(wp[L1_OFF + j]);
#pragma unroll
    for (int k = 0; k < H; ++k) {
#pragma unroll
        for (int j = 0; j < H; ++j)
            t1[j] = fma2p(h[k], wp[L1_OFF + H + k * H + j], t1[j]);
    }
#pragma unroll
    for (int j = 0; j < H; ++j) h[j] = relu2(t1[j]);

    // ---- L residual blocks ----
#pragma unroll 1
    for (int l = 0; l < L; ++l) {
        const int base = BLK_OFF + l * BLK_STRIDE;

        // t1 = relu(h @ W1 + B1)
#pragma unroll
        for (int j = 0; j < H; ++j) t1[j] = tov2(wp[base + j]);
#pragma unroll
        for (int k = 0; k < H; ++k) {
#pragma unroll
            for (int j = 0; j < H; ++j)
                t1[j] = fma2p(h[k], wp[base + 10 + k * H + j], t1[j]);
        }
#pragma unroll
        for (int j = 0; j < H; ++j) t1[j] = relu2(t1[j]);

        // t2 = (B2+B3) + h @ W2
#pragma unroll
        for (int j = 0; j < H; ++j) t2[j] = tov2(wp[base + 110 + j]);
#pragma unroll
        for (int k = 0; k < H; ++k) {
#pragma unroll
            for (int j = 0; j < H; ++j)
                t2[j] = fma2p(h[k], wp[base + 120 + k * H + j], t2[j]);
        }

        // t2 += t1 @ W3 ; h = relu(t2)
#pragma unroll
        for (int k = 0; k < H; ++k) {
#pragma unroll
            for (int j = 0; j < H; ++j)
                t2[j] = fma2p(t1[k], wp[base + 220 + k * H + j], t2[j]);
        }
#pragma unroll
        for (int j = 0; j < H; ++j) h[j] = relu2(t2[j]);
    }

    // ---- layer 8: 10 -> 10, relu ----
#pragma unroll
    for (int j = 0; j < H; ++j) t1[j] = tov2(wp[L8_OFF + j]);
#pragma unroll
    for (int k = 0; k < H; ++k) {
#pragma unroll
        for (int j = 0; j < H; ++j)
            t1[j] = fma2p(h[k], wp[L8_OFF + H + k * H + j], t1[j]);
    }
#pragma unroll
    for (int j = 0; j < H; ++j) h[j] = relu2(t1[j]);

    // ---- output layer: 10 -> 1 ----
    v2f o = tov2(wp[L9_OFF]);
#pragma unroll
    for (int k = 0; k < H; ++k) o = fma2p(h[k], wp[L9_OFF + 1 + k], o);

    *(v2f*)(out + 2 * (long)i) = o;
}

extern "C" void kernel_launch(void* const* d_in, const int* in_sizes, int n_in,
                              void* d_out, int out_size, void* d_ws, size_t ws_size,
                              hipStream_t stream)
{
    const float* x   = (const float*)d_in[0];
    const float* w0  = (const float*)d_in[1];
    const float* b0  = (const float*)d_in[2];
    const float* w1  = (const float*)d_in[3];
    const float* b1  = (const float*)d_in[4];
    const float* Wr1 = (const float*)d_in[5];
    const float* Br1 = (const float*)d_in[6];
    const float* Wr2 = (const float*)d_in[7];
    const float* Br2 = (const float*)d_in[8];
    const float* Wr3 = (const float*)d_in[9];
    const float* Br3 = (const float*)d_in[10];
    const float* w8  = (const float*)d_in[11];
    const float* b8  = (const float*)d_in[12];
    const float* w9  = (const float*)d_in[13];
    const float* b9  = (const float*)d_in[14];
    float* out = (float*)d_out;
    float2* wp = (float2*)d_ws;   // 3471 * 8 B = 27.8 KB, well under ws_size

    hipLaunchKernelGGL(prepack, dim3(1), dim3(256), 0, stream,
                       w0, b0, w1, b1, Wr1, Br1, Wr2, Br2, Wr3, Br3,
                       w8, b8, w9, b9, wp);

    dim3 block(256);
    dim3 grid(NPTS / 2 / 256);   // 2 points per thread
    hipLaunchKernelGGL(resnet_fwd, grid, block, 0, stream,
                       x, (const float2*)wp, out);
}